// Round 6
// baseline (881.836 us; speedup 1.0000x reference)
//
#include <hip/hip_runtime.h>
#include <hip/hip_bf16.h>

// SelfAttention (SAGAN) block, B=16 H=64 W=64 C=512, c8=64, c2=256.
// Input storage dtype (bf16 vs f32) detected at runtime; kernels templated.
//
// Workspace layout (bytes), total 20,448,256:
//   0        : dtype flag (int; 1 = float32, 0 = bf16)
//   787456   : wAllT  bf16 [384][512]  (transposed [wt|wp|wg], n-major) 393216 B
//   1311744  : theta   bf16 [16][4096][64]
//   9700352  : phi     bf16 [16][1024][64]
//   11797504 : gT      bf16 [16][256][1024]   (g conv output, TRANSPOSED)
//   20186112 : waT     bf16 [512][256]   (transposed normalized k_attn)
//
// d_out doubles as scratch: attn_kernel writes normalized O (attn_g, bf16,
// 512 B per row) into bytes [RB/2, RB) of each 512-elem output row
// (RB = 512*sizeof(T)); proj_kernel reads that slot for its own rows, then
// overwrites the full row with x + sigma*proj(O). Disjoint per-row, ordered
// by kernel boundaries -> race-free.

using bf16 = __hip_bfloat16;
typedef unsigned short u16;
typedef __attribute__((ext_vector_type(8))) short bf16x8;  // 8 bf16 = 4 VGPRs
typedef __attribute__((ext_vector_type(4))) float f32x4;

#define MFMA16(a, b, c) __builtin_amdgcn_mfma_f32_16x16x32_bf16((a), (b), (c), 0, 0, 0)

#define WS_FLAG   0
#define WS_WAT2   787456
#define WS_THETA  1311744
#define WS_PHI    9700352
#define WS_G      11797504
#define WS_WAT    20186112
#define WS_TOTAL  20448256

__device__ __forceinline__ float bf2f(bf16 v) { return __bfloat162float(v); }
__device__ __forceinline__ bf16 f2bf(float v) { return __float2bfloat16(v); }
__device__ __forceinline__ u16 f2bf_bits(float v) { bf16 h = f2bf(v); return *(u16*)&h; }

template <typename T> struct io;
template <> struct io<bf16> {
  static __device__ __forceinline__ float ld(const bf16* p) { return bf2f(*p); }
  static __device__ __forceinline__ void st(bf16* p, float v) { *p = f2bf(v); }
  static __device__ __forceinline__ int tag() { return 0; }
};
template <> struct io<float> {
  static __device__ __forceinline__ float ld(const float* p) { return *p; }
  static __device__ __forceinline__ void st(float* p, float v) { *p = v; }
  static __device__ __forceinline__ int tag() { return 1; }
};

// --------------- Kernel 0: detect input storage dtype ----------------------
__global__ __launch_bounds__(256) void detect_kernel(const void* xraw, int* flag) {
  const uint4* p = (const uint4*)xraw;   // scan first 131072 B as dwords
  int t = threadIdx.x;
  int cnt = 0;
#pragma unroll 8
  for (int i = 0; i < 32; ++i) {
    uint4 v = p[t + i * 256];
    unsigned d[4] = {v.x, v.y, v.z, v.w};
#pragma unroll
    for (int k = 0; k < 4; ++k) {
      if ((d[k] & 0x7F80u) == 0x7F80u) cnt++;
      if ((d[k] & 0x7F800000u) == 0x7F800000u) cnt++;
    }
  }
#pragma unroll
  for (int o = 32; o > 0; o >>= 1) cnt += __shfl_down(cnt, o, 64);
  __shared__ int red[4];
  if ((t & 63) == 0) red[t >> 6] = cnt;
  __syncthreads();
  if (t == 0) flag[0] = (red[0] + red[1] + red[2] + red[3] > 4) ? 1 : 0;
}

__device__ __forceinline__ float block_sum_256(float x, float* red) {
#pragma unroll
  for (int o = 32; o > 0; o >>= 1) x += __shfl_down(x, o, 64);
  __syncthreads();
  if ((threadIdx.x & 63) == 0) red[threadIdx.x >> 6] = x;
  __syncthreads();
  return red[0] + red[1] + red[2] + red[3];
}

// ---------------- Kernel 1: spectral norm of all 4 weights -----------------
// Phase A wave-per-row with lane-parallel coalesced loads + shuffle reduce,
// phase B 4 partial accumulators + unroll; compile-time dims via template.
template <typename T, int CIN, int COUT, int MODE>
__device__ __forceinline__ void sn_impl(const T* w, const T* u,
                                        u16* wAllT, u16* waT) {
  __shared__ float v[CIN];
  __shared__ float red[4];
  const int t = threadIdx.x, wv = t >> 6, ln = t & 63;

  // preload u into registers (lane-strided)
  float uv[COUT / 64];
#pragma unroll
  for (int jj = 0; jj < COUT / 64; ++jj) uv[jj] = io<T>::ld(u + jj * 64 + ln);

  // ---- phase A: v[i] = sum_j u[j]*W[i][j], one wave per row ----
#pragma unroll 2
  for (int i = wv; i < CIN; i += 4) {
    float acc = 0.f;
#pragma unroll
    for (int jj = 0; jj < COUT / 64; ++jj)
      acc += uv[jj] * io<T>::ld(w + (size_t)i * COUT + jj * 64 + ln);
#pragma unroll
    for (int o = 32; o > 0; o >>= 1) acc += __shfl_down(acc, o, 64);
    if (ln == 0) v[i] = acc;
  }
  __syncthreads();
  float loc = 0.f;
  for (int i = t; i < CIN; i += 256) loc += v[i] * v[i];
  float s1 = block_sum_256(loc, red);
  float inv1 = 1.f / (sqrtf(s1) + 1e-12f);

  // ---- phase B: u2[j] = inv1 * sum_i v[i]*W[i][j]; coalesced over j ----
  float loc2 = 0.f;
#pragma unroll
  for (int j0 = 0; j0 < COUT; j0 += 256) {
    int j = j0 + t;
    if (j < COUT) {
      float a0 = 0.f, a1 = 0.f, a2 = 0.f, a3 = 0.f;
#pragma unroll 4
      for (int i = 0; i < CIN; i += 4) {
        a0 += v[i + 0] * io<T>::ld(w + (size_t)(i + 0) * COUT + j);
        a1 += v[i + 1] * io<T>::ld(w + (size_t)(i + 1) * COUT + j);
        a2 += v[i + 2] * io<T>::ld(w + (size_t)(i + 2) * COUT + j);
        a3 += v[i + 3] * io<T>::ld(w + (size_t)(i + 3) * COUT + j);
      }
      float acc = ((a0 + a1) + (a2 + a3)) * inv1;
      loc2 += acc * acc;
    }
  }
  float s2 = block_sum_256(loc2, red);
  float sigma = s2 / (sqrtf(s2) + 1e-12f);
  float winv = 1.f / sigma;

  // ---- phase C: write bf16 transposed copy ----
#pragma unroll 4
  for (int k = t; k < CIN * COUT; k += 256) {
    float val = io<T>::ld(w + k) * winv;
    u16 bits = f2bf_bits(val);
    int i = k / COUT, j = k % COUT;   // COUT pow2 -> shifts
    if constexpr (MODE == 0) wAllT[(size_t)j * 512 + i] = bits;
    if constexpr (MODE == 1) wAllT[(size_t)(64 + j) * 512 + i] = bits;
    if constexpr (MODE == 2) wAllT[(size_t)(128 + j) * 512 + i] = bits;
    if constexpr (MODE == 3) waT[(size_t)j * 256 + i] = bits;
  }
}

template <typename T>
__global__ __launch_bounds__(256) void sn_kernel(
    const void* ktv, const void* utv, const void* kpv, const void* upv,
    const void* kgv, const void* ugv, const void* kav, const void* uav,
    u16* wAllT, u16* waT, const int* flag) {
  if (flag[0] != io<T>::tag()) return;
  switch (blockIdx.x) {
    case 0:  sn_impl<T, 512, 64, 0>((const T*)ktv, (const T*)utv, wAllT, waT); break;
    case 1:  sn_impl<T, 512, 64, 1>((const T*)kpv, (const T*)upv, wAllT, waT); break;
    case 2:  sn_impl<T, 512, 256, 2>((const T*)kgv, (const T*)ugv, wAllT, waT); break;
    default: sn_impl<T, 256, 512, 3>((const T*)kav, (const T*)uav, wAllT, waT); break;
  }
}

// ------ Kernel 2: MFMA fused theta/phi/g convs + 2x2 maxpool ---------------
// Grid: 16 batches x 64 tiles (each tile = 4x4 pooled windows = 64 pixels).
// Block GEMM: X[64 pix][512] @ W[512][384] with mfma_f32_16x16x32_bf16.
// g output is written TRANSPOSED: gT[bb][ch][pooled_pixel].
template <typename T>
__global__ __launch_bounds__(256, 2) void conv3_mfma_kernel(
    const void* xv, const u16* __restrict__ wAllT,
    bf16* __restrict__ theta, bf16* __restrict__ phi, bf16* __restrict__ gT,
    const int* flag) {
  if (flag[0] != io<T>::tag()) return;
  constexpr bool SPLIT = sizeof(T) == 4;   // f32 input -> hi/lo split
  const T* x = (const T*)xv;

  __shared__ u16 xh_s[2][64][136];         // +8 pad: 272B row stride
  __shared__ u16 xl_s[2][64][136];

  const int tid = threadIdx.x;
  const int w = tid >> 6;
  const int lane = tid & 63;
  const int quad = lane >> 4;
  const int l15 = lane & 15;
  const int bb = blockIdx.x >> 6;
  const int tile = blockIdx.x & 63;
  const int pth = tile >> 3, ptw = tile & 7;   // pooled 4x4 tile origin /4

  const int sp = tid >> 2;
  const int sq = tid & 3;
  const int swin = sp >> 2, sd = sp & 3;
  const int sh = 2 * (pth * 4 + (swin >> 2)) + (sd >> 1);
  const int sw = 2 * (ptw * 4 + (swin & 3)) + (sd & 1);
  const T* xrow = x + ((size_t)(bb * 64 + sh) * 64 + sw) * 512 + sq * 32;

  auto STAGE = [&](int buf, int kc) {
    if constexpr (SPLIT) {
      const float* src = (const float*)xrow + kc * 128;
#pragma unroll
      for (int hl = 0; hl < 2; ++hl) {
        float f[16];
#pragma unroll
        for (int i = 0; i < 4; ++i) {
          float4 v4 = ((const float4*)src)[hl * 4 + i];
          f[4 * i] = v4.x; f[4 * i + 1] = v4.y; f[4 * i + 2] = v4.z; f[4 * i + 3] = v4.w;
        }
        unsigned ph_[8], pl_[8];
#pragma unroll
        for (int i = 0; i < 8; ++i) {
          float a = f[2 * i], b = f[2 * i + 1];
          u16 ha = f2bf_bits(a), hb = f2bf_bits(b);
          float ra = a - __uint_as_float((unsigned)ha << 16);
          float rb = b - __uint_as_float((unsigned)hb << 16);
          ph_[i] = (unsigned)ha | ((unsigned)hb << 16);
          pl_[i] = (unsigned)f2bf_bits(ra) | ((unsigned)f2bf_bits(rb) << 16);
        }
        *(uint4*)&xh_s[buf][sp][sq * 32 + hl * 16] =
            make_uint4(ph_[0], ph_[1], ph_[2], ph_[3]);
        *(uint4*)&xh_s[buf][sp][sq * 32 + hl * 16 + 8] =
            make_uint4(ph_[4], ph_[5], ph_[6], ph_[7]);
        *(uint4*)&xl_s[buf][sp][sq * 32 + hl * 16] =
            make_uint4(pl_[0], pl_[1], pl_[2], pl_[3]);
        *(uint4*)&xl_s[buf][sp][sq * 32 + hl * 16 + 8] =
            make_uint4(pl_[4], pl_[5], pl_[6], pl_[7]);
      }
    } else {
      const u16* src = (const u16*)xrow + kc * 128;
#pragma unroll
      for (int i = 0; i < 4; ++i)
        *(uint4*)&xh_s[buf][sp][sq * 32 + i * 8] = ((const uint4*)src)[i];
    }
  };

  f32x4 acc[4][6];
#pragma unroll
  for (int mt = 0; mt < 4; ++mt)
#pragma unroll
    for (int nt = 0; nt < 6; ++nt) acc[mt][nt] = (f32x4){0.f, 0.f, 0.f, 0.f};

  const u16* wb = wAllT + (size_t)(w * 96 + l15) * 512 + quad * 8;

  STAGE(0, 0);
  __syncthreads();
#pragma unroll 1
  for (int kc = 0; kc < 4; ++kc) {
    const int buf = kc & 1;
    if (kc < 3) STAGE(buf ^ 1, kc + 1);
#pragma unroll
    for (int ks = 0; ks < 4; ++ks) {
      bf16x8 ah[4], al[4];
#pragma unroll
      for (int mt = 0; mt < 4; ++mt) {
        ah[mt] = *(const bf16x8*)&xh_s[buf][mt * 16 + l15][ks * 32 + quad * 8];
        if constexpr (SPLIT)
          al[mt] = *(const bf16x8*)&xl_s[buf][mt * 16 + l15][ks * 32 + quad * 8];
      }
#pragma unroll
      for (int nt = 0; nt < 6; ++nt) {
        bf16x8 b = *(const bf16x8*)(wb + (size_t)nt * 16 * 512 + kc * 128 + ks * 32);
#pragma unroll
        for (int mt = 0; mt < 4; ++mt) {
          acc[mt][nt] = MFMA16(ah[mt], b, acc[mt][nt]);
          if constexpr (SPLIT) acc[mt][nt] = MFMA16(al[mt], b, acc[mt][nt]);
        }
      }
    }
    __syncthreads();
  }

  // ---- epilogue: theta unpooled, phi pooled, g pooled + TRANSPOSED ----
#pragma unroll
  for (int nt = 0; nt < 6; ++nt) {
    const int nb = w * 96 + nt * 16;       // wave-uniform
    const int n = nb + l15;
    if (nb < 64) {                         // theta
#pragma unroll
      for (int mt = 0; mt < 4; ++mt)
#pragma unroll
        for (int r = 0; r < 4; ++r) {
          int p = mt * 16 + quad * 4 + r;
          int win = p >> 2, d = p & 3;
          int h = 2 * (pth * 4 + (win >> 2)) + (d >> 1);
          int wc = 2 * (ptw * 4 + (win & 3)) + (d & 1);
          theta[((size_t)bb * 4096 + h * 64 + wc) * 64 + n] = f2bf(acc[mt][nt][r]);
        }
    } else if (nb < 128) {                 // phi (pooled)
      const int ch = n - 64;
#pragma unroll
      for (int mt = 0; mt < 4; ++mt) {
        int win = mt * 4 + quad;
        int pp = (pth * 4 + (win >> 2)) * 32 + (ptw * 4 + (win & 3));
        float mx = fmaxf(fmaxf(acc[mt][nt][0], acc[mt][nt][1]),
                         fmaxf(acc[mt][nt][2], acc[mt][nt][3]));
        phi[((size_t)bb * 1024 + pp) * 64 + ch] = f2bf(mx);
      }
    } else {                               // g (pooled, transposed)
      const int ch = n - 128;
#pragma unroll
      for (int mt = 0; mt < 4; ++mt) {
        int win = mt * 4 + quad;
        int pp = (pth * 4 + (win >> 2)) * 32 + (ptw * 4 + (win & 3));
        float mx = fmaxf(fmaxf(acc[mt][nt][0], acc[mt][nt][1]),
                         fmaxf(acc[mt][nt][2], acc[mt][nt][3]));
        gT[((size_t)bb * 256 + ch) * 1024 + pp] = f2bf(mx);
      }
    }
  }
}

// ---- Kernel 3: flash attention, 4 waves/block, 16 q/wave, 32-key chunks ---
// Round-5 postmortem: 32q/wave halved total waves (8/CU) and grew LDS/VGPR ->
// occupancy 11.6%, slower. The decomposition max is 16 waves/CU at 16q/wave;
// to reach it, LDS must not limit: 32-key chunks shrink LDS to ~26KB
// (ph_s[32][66] + gt_s[256][34] + p_s[4][16][34]), so residency is
// grid-limited (4 blocks/CU = 16 waves = 50% occ).
// + T14 register prefetch: chunk kc+1's global loads issue right after the
//   staging barrier, hiding L2 latency under chunk kc's compute.
// + T13 defer-max (THR=8): skip o[16] rescale unless running max grows >8.
// NO min-waves launch bound (round-3 spill lesson).
// A-frag: A[m=lane&15][k=quad*8+j]; B-frag: B[k=quad*8+j][n=lane&15];
// C/D:    col=lane&15, row=quad*4+reg.
template <typename T>
__global__ __launch_bounds__(256) void attn_kernel(
    const bf16* __restrict__ thetab, const bf16* __restrict__ phib,
    const bf16* __restrict__ gTb, void* __restrict__ outv, const int* flag) {
  if (flag[0] != io<T>::tag()) return;
  __shared__ u16 ph_s[32][66];     //  4224 B  (stride 33 dw, ~conflict-free)
  __shared__ u16 gt_s[256][34];    // 17408 B  (stride 17 dw)
  __shared__ u16 p_s[4][16][34];   //  4352 B

  const int tid = threadIdx.x;
  const int w = tid >> 6;
  const int lane = tid & 63;
  const int quad = lane >> 4;
  const int l15 = lane & 15;
  const int qt = blockIdx.x * 4 + w;     // 16-query tile index, 4096 total
  const int bb = qt >> 8;                // same for all 4 waves of a block
  const int q0 = (qt & 255) * 16;

  const u16* th = (const u16*)thetab + ((size_t)bb * 4096 + q0 + l15) * 64 + quad * 8;
  const bf16x8 a0 = *(const bf16x8*)th;
  const bf16x8 a1 = *(const bf16x8*)(th + 32);

  const u16* ph = (const u16*)phib + (size_t)bb * 1024 * 64;
  const u16* gT = (const u16*)gTb + (size_t)bb * 256 * 1024;

  f32x4 o[16];
#pragma unroll
  for (int i = 0; i < 16; ++i) o[i] = (f32x4){0.f, 0.f, 0.f, 0.f};
  float mold[4] = {-1e30f, -1e30f, -1e30f, -1e30f};
  float lsum[4] = {0.f, 0.f, 0.f, 0.f};

  // staging coords (block-wide): phi 32x64 (16B/thr), gT 256x32 (64B/thr)
  const int pr = tid >> 3, pc = (tid & 7) * 8;
  const int gr = tid >> 2, gq = (tid & 3) * 8;

  uint4 pf_p, pf_g[4];
  auto LOAD = [&](int kc) {
    pf_p = *(const uint4*)(ph + ((kc * 32 + pr) * 64 + pc));
#pragma unroll
    for (int i = 0; i < 4; ++i)
      pf_g[i] = *(const uint4*)(gT + (size_t)(i * 64 + gr) * 1024 + kc * 32 + gq);
  };
  LOAD(0);

#pragma unroll 1
  for (int kc = 0; kc < 32; ++kc) {
    __syncthreads();               // prev chunk's LDS reads complete
    *(uint4*)&ph_s[pr][pc] = pf_p;
#pragma unroll
    for (int i = 0; i < 4; ++i)
      *(uint4*)&gt_s[i * 64 + gr][gq] = pf_g[i];
    __syncthreads();
    if (kc < 31) LOAD(kc + 1);     // prefetch next chunk under compute

    // ---- QK^T: S[16 q][32 keys] ----
    f32x4 s[2];
#pragma unroll
    for (int t4 = 0; t4 < 2; ++t4) {
      bf16x8 b0 = *(const bf16x8*)&ph_s[t4 * 16 + l15][quad * 8];
      bf16x8 b1 = *(const bf16x8*)&ph_s[t4 * 16 + l15][32 + quad * 8];
      f32x4 z = (f32x4){0.f, 0.f, 0.f, 0.f};
      z = MFMA16(a0, b0, z);
      z = MFMA16(a1, b1, z);
      s[t4] = z;
    }
    // ---- online softmax with defer-max (rows = quad*4+r) ----
    float rmax[4], alpha[4], rsum[4];
    bool need = false;
#pragma unroll
    for (int r = 0; r < 4; ++r) {
      rmax[r] = fmaxf(s[0][r], s[1][r]);
#pragma unroll
      for (int m = 1; m <= 8; m <<= 1) rmax[r] = fmaxf(rmax[r], __shfl_xor(rmax[r], m, 64));
      bool upd = rmax[r] > mold[r] + 8.f;
      alpha[r] = upd ? __expf(mold[r] - rmax[r]) : 1.f;
      if (upd) mold[r] = rmax[r];
      need |= upd;
      rsum[r] = 0.f;
    }
#pragma unroll
    for (int t4 = 0; t4 < 2; ++t4)
#pragma unroll
      for (int r = 0; r < 4; ++r) {
        float pv = __expf(s[t4][r] - mold[r]);
        rsum[r] += pv;
        p_s[w][quad * 4 + r][t4 * 16 + l15] = f2bf_bits(pv);
      }
#pragma unroll
    for (int r = 0; r < 4; ++r)
#pragma unroll
      for (int m = 1; m <= 8; m <<= 1) rsum[r] += __shfl_xor(rsum[r], m, 64);
    if (__any(need)) {
#pragma unroll
      for (int i = 0; i < 16; ++i) {
        o[i][0] *= alpha[0]; o[i][1] *= alpha[1];
        o[i][2] *= alpha[2]; o[i][3] *= alpha[3];
      }
#pragma unroll
      for (int r = 0; r < 4; ++r) lsum[r] = lsum[r] * alpha[r] + rsum[r];
    } else {
#pragma unroll
      for (int r = 0; r < 4; ++r) lsum[r] += rsum[r];
    }
    // ---- PV: O += P @ Gchunk (K=32 -> one MFMA per output tile) ----
    bf16x8 pa = *(const bf16x8*)&p_s[w][l15][quad * 8];
#pragma unroll
    for (int t4 = 0; t4 < 16; ++t4) {
      bf16x8 b = *(const bf16x8*)&gt_s[t4 * 16 + l15][quad * 8];
      o[t4] = MFMA16(pa, b, o[t4]);
    }
  }

  // ---- normalize, write O (bf16) to per-row scratch slot in d_out ----
  const size_t RB = 512 * sizeof(T);
  char* ob = (char*)outv;
  float inv[4];
#pragma unroll
  for (int r = 0; r < 4; ++r) inv[r] = 1.f / lsum[r];
#pragma unroll
  for (int t4 = 0; t4 < 16; ++t4)
#pragma unroll
    for (int r = 0; r < 4; ++r) {
      size_t row = (size_t)bb * 4096 + q0 + quad * 4 + r;
      u16* dst = (u16*)(ob + row * RB + RB / 2) + t4 * 16 + l15;
      *dst = f2bf_bits(o[t4][r] * inv[r]);
    }
}

// ---- Kernel 4: projection GEMM O[64][256] @ waT^T + residual --------------
template <typename T>
__global__ __launch_bounds__(256, 3) void proj_kernel(
    const u16* __restrict__ waT, const void* __restrict__ xv,
    const void* __restrict__ sigv, void* __restrict__ outv, const int* flag) {
  if (flag[0] != io<T>::tag()) return;
  const T* xp = (const T*)xv;
  T* outp = (T*)outv;
  __shared__ u16 a_s[64][264];

  const int tid = threadIdx.x;
  const int w = tid >> 6;
  const int lane = tid & 63;
  const int quad = lane >> 4;
  const int l15 = lane & 15;
  const int R0 = blockIdx.x * 64;
  const size_t RB = 512 * sizeof(T);

  // ---- stage O rows from the d_out scratch slots ----
  {
    int row = tid >> 2, seg = tid & 3;
    const uint4* src = (const uint4*)((const char*)outv + (size_t)(R0 + row) * RB + RB / 2);
#pragma unroll
    for (int i = 0; i < 8; ++i)
      *(uint4*)&a_s[row][seg * 64 + i * 8] = src[seg * 8 + i];
  }
  __syncthreads();

  float sg = io<T>::ld((const T*)sigv);
#pragma unroll 1
  for (int h = 0; h < 2; ++h) {
    f32x4 pc[16];
#pragma unroll
    for (int i = 0; i < 16; ++i) pc[i] = (f32x4){0.f, 0.f, 0.f, 0.f};
#pragma unroll 1
    for (int ks = 0; ks < 8; ++ks) {
      bf16x8 a = *(const bf16x8*)&a_s[w * 16 + l15][ks * 32 + quad * 8];
#pragma unroll
      for (int t4 = 0; t4 < 16; ++t4) {
        bf16x8 b = *(const bf16x8*)(waT + (size_t)(h * 256 + t4 * 16 + l15) * 256 + ks * 32 + quad * 8);
        pc[t4] = MFMA16(a, b, pc[t4]);
      }
    }
#pragma unroll
    for (int t4 = 0; t4 < 16; ++t4)
#pragma unroll
      for (int r = 0; r < 4; ++r) {
        int row = R0 + w * 16 + quad * 4 + r;
        int col = h * 256 + t4 * 16 + l15;
        size_t off = (size_t)row * 512 + col;
        io<T>::st(outp + off, io<T>::ld(xp + off) + sg * pc[t4][r]);
      }
  }
}

extern "C" void kernel_launch(void* const* d_in, const int* in_sizes, int n_in,
                              void* d_out, int out_size, void* d_ws, size_t ws_size,
                              hipStream_t stream) {
  if (ws_size < (size_t)WS_TOTAL) return;
  char* ws = (char*)d_ws;
  int*   flag  = (int*)(ws + WS_FLAG);
  u16*   wAllT = (u16*)(ws + WS_WAT2);
  bf16*  theta = (bf16*)(ws + WS_THETA);
  bf16*  phi   = (bf16*)(ws + WS_PHI);
  bf16*  gT    = (bf16*)(ws + WS_G);
  u16*   waT   = (u16*)(ws + WS_WAT);

  detect_kernel<<<1, 256, 0, stream>>>(d_in[0], flag);

  sn_kernel<bf16><<<4, 256, 0, stream>>>(d_in[1], d_in[2], d_in[3], d_in[4],
                                         d_in[5], d_in[6], d_in[7], d_in[8],
                                         wAllT, waT, flag);
  sn_kernel<float><<<4, 256, 0, stream>>>(d_in[1], d_in[2], d_in[3], d_in[4],
                                          d_in[5], d_in[6], d_in[7], d_in[8],
                                          wAllT, waT, flag);

  conv3_mfma_kernel<bf16><<<1024, 256, 0, stream>>>(d_in[0], wAllT, theta, phi, gT, flag);
  conv3_mfma_kernel<float><<<1024, 256, 0, stream>>>(d_in[0], wAllT, theta, phi, gT, flag);

  attn_kernel<bf16><<<1024, 256, 0, stream>>>(theta, phi, gT, d_out, flag);
  attn_kernel<float><<<1024, 256, 0, stream>>>(theta, phi, gT, d_out, flag);

  proj_kernel<bf16><<<1024, 256, 0, stream>>>(waT, d_in[0], d_in[9], d_out, flag);
  proj_kernel<float><<<1024, 256, 0, stream>>>(waT, d_in[0], d_in[9], d_out, flag);
}

// Round 7
// 739.725 us; speedup vs baseline: 1.1921x; 1.1921x over previous
//
#include <hip/hip_runtime.h>
#include <hip/hip_bf16.h>

// SelfAttention (SAGAN) block, B=16 H=64 W=64 C=512, c8=64, c2=256.
// Input storage dtype (bf16 vs f32) detected at runtime; kernels templated.
//
// Workspace layout (bytes), total 20,448,256:
//   0        : dtype flag (int; 1 = float32, 0 = bf16)
//   787456   : wAllT  bf16 [384][512]  (transposed [wt|wp|wg], n-major) 393216 B
//   1311744  : theta   bf16 [16][4096][64]
//   9700352  : phi     bf16 [16][1024][64]
//   11797504 : gT      bf16 [16][256][1024]   (g conv output, TRANSPOSED)
//   20186112 : waT     bf16 [512][256]   (transposed normalized k_attn)
//
// d_out doubles as scratch: attn_kernel writes normalized O (attn_g, bf16,
// 512 B per row) into bytes [RB/2, RB) of each 512-elem output row
// (RB = 512*sizeof(T)); proj_kernel reads that slot for its own rows, then
// overwrites the full row with x + sigma*proj(O). Disjoint per-row, ordered
// by kernel boundaries -> race-free.

using bf16 = __hip_bfloat16;
typedef unsigned short u16;
typedef __attribute__((ext_vector_type(8))) short bf16x8;  // 8 bf16 = 4 VGPRs
typedef __attribute__((ext_vector_type(4))) float f32x4;

#define MFMA16(a, b, c) __builtin_amdgcn_mfma_f32_16x16x32_bf16((a), (b), (c), 0, 0, 0)

#define WS_FLAG   0
#define WS_WAT2   787456
#define WS_THETA  1311744
#define WS_PHI    9700352
#define WS_G      11797504
#define WS_WAT    20186112
#define WS_TOTAL  20448256

__device__ __forceinline__ float bf2f(bf16 v) { return __bfloat162float(v); }
__device__ __forceinline__ bf16 f2bf(float v) { return __float2bfloat16(v); }
__device__ __forceinline__ u16 f2bf_bits(float v) { bf16 h = f2bf(v); return *(u16*)&h; }

template <typename T> struct io;
template <> struct io<bf16> {
  static __device__ __forceinline__ float ld(const bf16* p) { return bf2f(*p); }
  static __device__ __forceinline__ void st(bf16* p, float v) { *p = f2bf(v); }
  static __device__ __forceinline__ int tag() { return 0; }
};
template <> struct io<float> {
  static __device__ __forceinline__ float ld(const float* p) { return *p; }
  static __device__ __forceinline__ void st(float* p, float v) { *p = v; }
  static __device__ __forceinline__ int tag() { return 1; }
};

// --------------- Kernel 0: detect input storage dtype ----------------------
__global__ __launch_bounds__(256) void detect_kernel(const void* xraw, int* flag) {
  const uint4* p = (const uint4*)xraw;   // scan first 131072 B as dwords
  int t = threadIdx.x;
  int cnt = 0;
#pragma unroll 8
  for (int i = 0; i < 32; ++i) {
    uint4 v = p[t + i * 256];
    unsigned d[4] = {v.x, v.y, v.z, v.w};
#pragma unroll
    for (int k = 0; k < 4; ++k) {
      if ((d[k] & 0x7F80u) == 0x7F80u) cnt++;
      if ((d[k] & 0x7F800000u) == 0x7F800000u) cnt++;
    }
  }
#pragma unroll
  for (int o = 32; o > 0; o >>= 1) cnt += __shfl_down(cnt, o, 64);
  __shared__ int red[4];
  if ((t & 63) == 0) red[t >> 6] = cnt;
  __syncthreads();
  if (t == 0) flag[0] = (red[0] + red[1] + red[2] + red[3] > 4) ? 1 : 0;
}

__device__ __forceinline__ float block_sum_256(float x, float* red) {
#pragma unroll
  for (int o = 32; o > 0; o >>= 1) x += __shfl_down(x, o, 64);
  __syncthreads();
  if ((threadIdx.x & 63) == 0) red[threadIdx.x >> 6] = x;
  __syncthreads();
  return red[0] + red[1] + red[2] + red[3];
}

// ---------------- Kernel 1: spectral norm of all 4 weights -----------------
// Phase A wave-per-row with lane-parallel coalesced loads + shuffle reduce,
// phase B 4 partial accumulators + unroll; compile-time dims via template.
template <typename T, int CIN, int COUT, int MODE>
__device__ __forceinline__ void sn_impl(const T* w, const T* u,
                                        u16* wAllT, u16* waT) {
  __shared__ float v[CIN];
  __shared__ float red[4];
  const int t = threadIdx.x, wv = t >> 6, ln = t & 63;

  // preload u into registers (lane-strided)
  float uv[COUT / 64];
#pragma unroll
  for (int jj = 0; jj < COUT / 64; ++jj) uv[jj] = io<T>::ld(u + jj * 64 + ln);

  // ---- phase A: v[i] = sum_j u[j]*W[i][j], one wave per row ----
#pragma unroll 2
  for (int i = wv; i < CIN; i += 4) {
    float acc = 0.f;
#pragma unroll
    for (int jj = 0; jj < COUT / 64; ++jj)
      acc += uv[jj] * io<T>::ld(w + (size_t)i * COUT + jj * 64 + ln);
#pragma unroll
    for (int o = 32; o > 0; o >>= 1) acc += __shfl_down(acc, o, 64);
    if (ln == 0) v[i] = acc;
  }
  __syncthreads();
  float loc = 0.f;
  for (int i = t; i < CIN; i += 256) loc += v[i] * v[i];
  float s1 = block_sum_256(loc, red);
  float inv1 = 1.f / (sqrtf(s1) + 1e-12f);

  // ---- phase B: u2[j] = inv1 * sum_i v[i]*W[i][j]; coalesced over j ----
  float loc2 = 0.f;
#pragma unroll
  for (int j0 = 0; j0 < COUT; j0 += 256) {
    int j = j0 + t;
    if (j < COUT) {
      float a0 = 0.f, a1 = 0.f, a2 = 0.f, a3 = 0.f;
#pragma unroll 4
      for (int i = 0; i < CIN; i += 4) {
        a0 += v[i + 0] * io<T>::ld(w + (size_t)(i + 0) * COUT + j);
        a1 += v[i + 1] * io<T>::ld(w + (size_t)(i + 1) * COUT + j);
        a2 += v[i + 2] * io<T>::ld(w + (size_t)(i + 2) * COUT + j);
        a3 += v[i + 3] * io<T>::ld(w + (size_t)(i + 3) * COUT + j);
      }
      float acc = ((a0 + a1) + (a2 + a3)) * inv1;
      loc2 += acc * acc;
    }
  }
  float s2 = block_sum_256(loc2, red);
  float sigma = s2 / (sqrtf(s2) + 1e-12f);
  float winv = 1.f / sigma;

  // ---- phase C: write bf16 transposed copy ----
#pragma unroll 4
  for (int k = t; k < CIN * COUT; k += 256) {
    float val = io<T>::ld(w + k) * winv;
    u16 bits = f2bf_bits(val);
    int i = k / COUT, j = k % COUT;   // COUT pow2 -> shifts
    if constexpr (MODE == 0) wAllT[(size_t)j * 512 + i] = bits;
    if constexpr (MODE == 1) wAllT[(size_t)(64 + j) * 512 + i] = bits;
    if constexpr (MODE == 2) wAllT[(size_t)(128 + j) * 512 + i] = bits;
    if constexpr (MODE == 3) waT[(size_t)j * 256 + i] = bits;
  }
}

template <typename T>
__global__ __launch_bounds__(256) void sn_kernel(
    const void* ktv, const void* utv, const void* kpv, const void* upv,
    const void* kgv, const void* ugv, const void* kav, const void* uav,
    u16* wAllT, u16* waT, const int* flag) {
  if (flag[0] != io<T>::tag()) return;
  switch (blockIdx.x) {
    case 0:  sn_impl<T, 512, 64, 0>((const T*)ktv, (const T*)utv, wAllT, waT); break;
    case 1:  sn_impl<T, 512, 64, 1>((const T*)kpv, (const T*)upv, wAllT, waT); break;
    case 2:  sn_impl<T, 512, 256, 2>((const T*)kgv, (const T*)ugv, wAllT, waT); break;
    default: sn_impl<T, 256, 512, 3>((const T*)kav, (const T*)uav, wAllT, waT); break;
  }
}

// ------ Kernel 2: MFMA fused theta/phi/g convs + 2x2 maxpool ---------------
// Grid: 16 batches x 64 tiles (each tile = 4x4 pooled windows = 64 pixels).
// Block GEMM: X[64 pix][512] @ W[512][384] with mfma_f32_16x16x32_bf16.
// g output is written TRANSPOSED: gT[bb][ch][pooled_pixel].
template <typename T>
__global__ __launch_bounds__(256, 2) void conv3_mfma_kernel(
    const void* xv, const u16* __restrict__ wAllT,
    bf16* __restrict__ theta, bf16* __restrict__ phi, bf16* __restrict__ gT,
    const int* flag) {
  if (flag[0] != io<T>::tag()) return;
  constexpr bool SPLIT = sizeof(T) == 4;   // f32 input -> hi/lo split
  const T* x = (const T*)xv;

  __shared__ u16 xh_s[2][64][136];         // +8 pad: 272B row stride
  __shared__ u16 xl_s[2][64][136];

  const int tid = threadIdx.x;
  const int w = tid >> 6;
  const int lane = tid & 63;
  const int quad = lane >> 4;
  const int l15 = lane & 15;
  const int bb = blockIdx.x >> 6;
  const int tile = blockIdx.x & 63;
  const int pth = tile >> 3, ptw = tile & 7;   // pooled 4x4 tile origin /4

  const int sp = tid >> 2;
  const int sq = tid & 3;
  const int swin = sp >> 2, sd = sp & 3;
  const int sh = 2 * (pth * 4 + (swin >> 2)) + (sd >> 1);
  const int sw = 2 * (ptw * 4 + (swin & 3)) + (sd & 1);
  const T* xrow = x + ((size_t)(bb * 64 + sh) * 64 + sw) * 512 + sq * 32;

  auto STAGE = [&](int buf, int kc) {
    if constexpr (SPLIT) {
      const float* src = (const float*)xrow + kc * 128;
#pragma unroll
      for (int hl = 0; hl < 2; ++hl) {
        float f[16];
#pragma unroll
        for (int i = 0; i < 4; ++i) {
          float4 v4 = ((const float4*)src)[hl * 4 + i];
          f[4 * i] = v4.x; f[4 * i + 1] = v4.y; f[4 * i + 2] = v4.z; f[4 * i + 3] = v4.w;
        }
        unsigned ph_[8], pl_[8];
#pragma unroll
        for (int i = 0; i < 8; ++i) {
          float a = f[2 * i], b = f[2 * i + 1];
          u16 ha = f2bf_bits(a), hb = f2bf_bits(b);
          float ra = a - __uint_as_float((unsigned)ha << 16);
          float rb = b - __uint_as_float((unsigned)hb << 16);
          ph_[i] = (unsigned)ha | ((unsigned)hb << 16);
          pl_[i] = (unsigned)f2bf_bits(ra) | ((unsigned)f2bf_bits(rb) << 16);
        }
        *(uint4*)&xh_s[buf][sp][sq * 32 + hl * 16] =
            make_uint4(ph_[0], ph_[1], ph_[2], ph_[3]);
        *(uint4*)&xh_s[buf][sp][sq * 32 + hl * 16 + 8] =
            make_uint4(ph_[4], ph_[5], ph_[6], ph_[7]);
        *(uint4*)&xl_s[buf][sp][sq * 32 + hl * 16] =
            make_uint4(pl_[0], pl_[1], pl_[2], pl_[3]);
        *(uint4*)&xl_s[buf][sp][sq * 32 + hl * 16 + 8] =
            make_uint4(pl_[4], pl_[5], pl_[6], pl_[7]);
      }
    } else {
      const u16* src = (const u16*)xrow + kc * 128;
#pragma unroll
      for (int i = 0; i < 4; ++i)
        *(uint4*)&xh_s[buf][sp][sq * 32 + i * 8] = ((const uint4*)src)[i];
    }
  };

  f32x4 acc[4][6];
#pragma unroll
  for (int mt = 0; mt < 4; ++mt)
#pragma unroll
    for (int nt = 0; nt < 6; ++nt) acc[mt][nt] = (f32x4){0.f, 0.f, 0.f, 0.f};

  const u16* wb = wAllT + (size_t)(w * 96 + l15) * 512 + quad * 8;

  STAGE(0, 0);
  __syncthreads();
#pragma unroll 1
  for (int kc = 0; kc < 4; ++kc) {
    const int buf = kc & 1;
    if (kc < 3) STAGE(buf ^ 1, kc + 1);
#pragma unroll
    for (int ks = 0; ks < 4; ++ks) {
      bf16x8 ah[4], al[4];
#pragma unroll
      for (int mt = 0; mt < 4; ++mt) {
        ah[mt] = *(const bf16x8*)&xh_s[buf][mt * 16 + l15][ks * 32 + quad * 8];
        if constexpr (SPLIT)
          al[mt] = *(const bf16x8*)&xl_s[buf][mt * 16 + l15][ks * 32 + quad * 8];
      }
#pragma unroll
      for (int nt = 0; nt < 6; ++nt) {
        bf16x8 b = *(const bf16x8*)(wb + (size_t)nt * 16 * 512 + kc * 128 + ks * 32);
#pragma unroll
        for (int mt = 0; mt < 4; ++mt) {
          acc[mt][nt] = MFMA16(ah[mt], b, acc[mt][nt]);
          if constexpr (SPLIT) acc[mt][nt] = MFMA16(al[mt], b, acc[mt][nt]);
        }
      }
    }
    __syncthreads();
  }

  // ---- epilogue: theta unpooled, phi pooled, g pooled + TRANSPOSED ----
#pragma unroll
  for (int nt = 0; nt < 6; ++nt) {
    const int nb = w * 96 + nt * 16;       // wave-uniform
    const int n = nb + l15;
    if (nb < 64) {                         // theta
#pragma unroll
      for (int mt = 0; mt < 4; ++mt)
#pragma unroll
        for (int r = 0; r < 4; ++r) {
          int p = mt * 16 + quad * 4 + r;
          int win = p >> 2, d = p & 3;
          int h = 2 * (pth * 4 + (win >> 2)) + (d >> 1);
          int wc = 2 * (ptw * 4 + (win & 3)) + (d & 1);
          theta[((size_t)bb * 4096 + h * 64 + wc) * 64 + n] = f2bf(acc[mt][nt][r]);
        }
    } else if (nb < 128) {                 // phi (pooled)
      const int ch = n - 64;
#pragma unroll
      for (int mt = 0; mt < 4; ++mt) {
        int win = mt * 4 + quad;
        int pp = (pth * 4 + (win >> 2)) * 32 + (ptw * 4 + (win & 3));
        float mx = fmaxf(fmaxf(acc[mt][nt][0], acc[mt][nt][1]),
                         fmaxf(acc[mt][nt][2], acc[mt][nt][3]));
        phi[((size_t)bb * 1024 + pp) * 64 + ch] = f2bf(mx);
      }
    } else {                               // g (pooled, transposed)
      const int ch = n - 128;
#pragma unroll
      for (int mt = 0; mt < 4; ++mt) {
        int win = mt * 4 + quad;
        int pp = (pth * 4 + (win >> 2)) * 32 + (ptw * 4 + (win & 3));
        float mx = fmaxf(fmaxf(acc[mt][nt][0], acc[mt][nt][1]),
                         fmaxf(acc[mt][nt][2], acc[mt][nt][3]));
        gT[((size_t)bb * 256 + ch) * 1024 + pp] = f2bf(mx);
      }
    }
  }
}

// ---- Kernel 3: flash attention, 4 waves/block, 16 q/wave, 64-key chunks ---
// Round-6 postmortem: 32-key chunks doubled barrier+softmax fixed costs and
// kept odd-dword LDS strides (b128 window overlap conflicts); occupancy never
// rose. Revert to the round-4 structure (best measured, 192us) with exactly
// two fixes:
//  (1) stride 68 u16 = 34 dw: b128 rows start at bank 2r mod 32 -> adjacent
//      rows overlap exactly 2 banks = 2-way = free [m136]. LDS becomes
//      8704+34816+8704 = 52224 B -> 3 blocks/CU (was 2) = +50% TLP.
//  (2) T13 defer-max (THR=8): skip o[16] rescale unless running max grows >8.
// No register prefetch (costs ~40 VGPR at 64-key chunks; TLP is cheaper).
// NO min-waves launch bound (round-3 spill lesson).
// A-frag: A[m=lane&15][k=quad*8+j]; B-frag: B[k=quad*8+j][n=lane&15];
// C/D:    col=lane&15, row=quad*4+reg.
template <typename T>
__global__ __launch_bounds__(256) void attn_kernel(
    const bf16* __restrict__ thetab, const bf16* __restrict__ phib,
    const bf16* __restrict__ gTb, void* __restrict__ outv, const int* flag) {
  if (flag[0] != io<T>::tag()) return;
  __shared__ u16 ph_s[64][68];     //  8704 B
  __shared__ u16 gt_s[256][68];    // 34816 B
  __shared__ u16 p_s[4][16][68];   //  8704 B   (total 52224 -> 3 blocks/CU)

  const int tid = threadIdx.x;
  const int w = tid >> 6;
  const int lane = tid & 63;
  const int quad = lane >> 4;
  const int l15 = lane & 15;
  const int qt = blockIdx.x * 4 + w;     // 16-query tile index, 4096 total
  const int bb = qt >> 8;                // same for all 4 waves of a block
  const int q0 = (qt & 255) * 16;

  const u16* th = (const u16*)thetab + ((size_t)bb * 4096 + q0 + l15) * 64 + quad * 8;
  const bf16x8 a0 = *(const bf16x8*)th;
  const bf16x8 a1 = *(const bf16x8*)(th + 32);

  const u16* ph = (const u16*)phib + (size_t)bb * 1024 * 64;
  const u16* gT = (const u16*)gTb + (size_t)bb * 256 * 1024;

  f32x4 o[16];
#pragma unroll
  for (int i = 0; i < 16; ++i) o[i] = (f32x4){0.f, 0.f, 0.f, 0.f};
  float mold[4] = {-1e30f, -1e30f, -1e30f, -1e30f};
  float lsum[4] = {0.f, 0.f, 0.f, 0.f};

  // staging coords (block-wide)
  const int pr = tid >> 2, pc = (tid & 3) * 16;       // phi: 32B/thread
  const int gr = tid >> 3, gc = (tid & 7) * 8;        // gT: 16B/thread, 8 iters

#pragma unroll 1
  for (int kc = 0; kc < 16; ++kc) {
    __syncthreads();               // prev chunk's LDS reads complete
    {
      const u16* src = ph + ((kc * 64 + pr) * 64 + pc);
      *(uint4*)&ph_s[pr][pc] = *(const uint4*)src;
      *(uint4*)&ph_s[pr][pc + 8] = *(const uint4*)(src + 8);
    }
#pragma unroll
    for (int i = 0; i < 8; ++i) {
      const u16* src = gT + (size_t)(i * 32 + gr) * 1024 + kc * 64 + gc;
      *(uint4*)&gt_s[i * 32 + gr][gc] = *(const uint4*)src;
    }
    __syncthreads();

    // ---- QK^T: S[16 q][64 keys] ----
    f32x4 s[4];
#pragma unroll
    for (int t4 = 0; t4 < 4; ++t4) {
      bf16x8 b0 = *(const bf16x8*)&ph_s[t4 * 16 + l15][quad * 8];
      bf16x8 b1 = *(const bf16x8*)&ph_s[t4 * 16 + l15][32 + quad * 8];
      f32x4 z = (f32x4){0.f, 0.f, 0.f, 0.f};
      z = MFMA16(a0, b0, z);
      z = MFMA16(a1, b1, z);
      s[t4] = z;
    }
    // ---- online softmax with defer-max (rows = quad*4+r) ----
    float rmax[4], alpha[4], rsum[4];
    bool need = false;
#pragma unroll
    for (int r = 0; r < 4; ++r) {
      rmax[r] = fmaxf(fmaxf(s[0][r], s[1][r]), fmaxf(s[2][r], s[3][r]));
#pragma unroll
      for (int m = 1; m <= 8; m <<= 1) rmax[r] = fmaxf(rmax[r], __shfl_xor(rmax[r], m, 64));
      bool upd = rmax[r] > mold[r] + 8.f;
      alpha[r] = upd ? __expf(mold[r] - rmax[r]) : 1.f;
      if (upd) mold[r] = rmax[r];
      need |= upd;
      rsum[r] = 0.f;
    }
#pragma unroll
    for (int t4 = 0; t4 < 4; ++t4)
#pragma unroll
      for (int r = 0; r < 4; ++r) {
        float pv = __expf(s[t4][r] - mold[r]);
        rsum[r] += pv;
        p_s[w][quad * 4 + r][t4 * 16 + l15] = f2bf_bits(pv);
      }
#pragma unroll
    for (int r = 0; r < 4; ++r)
#pragma unroll
      for (int m = 1; m <= 8; m <<= 1) rsum[r] += __shfl_xor(rsum[r], m, 64);
    if (__any(need)) {
#pragma unroll
      for (int i = 0; i < 16; ++i) {
        o[i][0] *= alpha[0]; o[i][1] *= alpha[1];
        o[i][2] *= alpha[2]; o[i][3] *= alpha[3];
      }
#pragma unroll
      for (int r = 0; r < 4; ++r) lsum[r] = lsum[r] * alpha[r] + rsum[r];
    } else {
#pragma unroll
      for (int r = 0; r < 4; ++r) lsum[r] += rsum[r];
    }
    // ---- PV: O += P @ Gchunk ----
    bf16x8 pa0 = *(const bf16x8*)&p_s[w][l15][quad * 8];
    bf16x8 pa1 = *(const bf16x8*)&p_s[w][l15][32 + quad * 8];
#pragma unroll
    for (int t4 = 0; t4 < 16; ++t4) {
      bf16x8 b0 = *(const bf16x8*)&gt_s[t4 * 16 + l15][quad * 8];
      bf16x8 b1 = *(const bf16x8*)&gt_s[t4 * 16 + l15][32 + quad * 8];
      o[t4] = MFMA16(pa0, b0, o[t4]);
      o[t4] = MFMA16(pa1, b1, o[t4]);
    }
  }

  // ---- normalize, write O (bf16) to per-row scratch slot in d_out ----
  const size_t RB = 512 * sizeof(T);
  char* ob = (char*)outv;
  float inv[4];
#pragma unroll
  for (int r = 0; r < 4; ++r) inv[r] = 1.f / lsum[r];
#pragma unroll
  for (int t4 = 0; t4 < 16; ++t4)
#pragma unroll
    for (int r = 0; r < 4; ++r) {
      size_t row = (size_t)bb * 4096 + q0 + quad * 4 + r;
      u16* dst = (u16*)(ob + row * RB + RB / 2) + t4 * 16 + l15;
      *dst = f2bf_bits(o[t4][r] * inv[r]);
    }
}

// ---- Kernel 4: projection GEMM O[64][256] @ waT^T + residual --------------
template <typename T>
__global__ __launch_bounds__(256, 3) void proj_kernel(
    const u16* __restrict__ waT, const void* __restrict__ xv,
    const void* __restrict__ sigv, void* __restrict__ outv, const int* flag) {
  if (flag[0] != io<T>::tag()) return;
  const T* xp = (const T*)xv;
  T* outp = (T*)outv;
  __shared__ u16 a_s[64][264];

  const int tid = threadIdx.x;
  const int w = tid >> 6;
  const int lane = tid & 63;
  const int quad = lane >> 4;
  const int l15 = lane & 15;
  const int R0 = blockIdx.x * 64;
  const size_t RB = 512 * sizeof(T);

  // ---- stage O rows from the d_out scratch slots ----
  {
    int row = tid >> 2, seg = tid & 3;
    const uint4* src = (const uint4*)((const char*)outv + (size_t)(R0 + row) * RB + RB / 2);
#pragma unroll
    for (int i = 0; i < 8; ++i)
      *(uint4*)&a_s[row][seg * 64 + i * 8] = src[seg * 8 + i];
  }
  __syncthreads();

  float sg = io<T>::ld((const T*)sigv);
#pragma unroll 1
  for (int h = 0; h < 2; ++h) {
    f32x4 pc[16];
#pragma unroll
    for (int i = 0; i < 16; ++i) pc[i] = (f32x4){0.f, 0.f, 0.f, 0.f};
#pragma unroll 1
    for (int ks = 0; ks < 8; ++ks) {
      bf16x8 a = *(const bf16x8*)&a_s[w * 16 + l15][ks * 32 + quad * 8];
#pragma unroll
      for (int t4 = 0; t4 < 16; ++t4) {
        bf16x8 b = *(const bf16x8*)(waT + (size_t)(h * 256 + t4 * 16 + l15) * 256 + ks * 32 + quad * 8);
        pc[t4] = MFMA16(a, b, pc[t4]);
      }
    }
#pragma unroll
    for (int t4 = 0; t4 < 16; ++t4)
#pragma unroll
      for (int r = 0; r < 4; ++r) {
        int row = R0 + w * 16 + quad * 4 + r;
        int col = h * 256 + t4 * 16 + l15;
        size_t off = (size_t)row * 512 + col;
        io<T>::st(outp + off, io<T>::ld(xp + off) + sg * pc[t4][r]);
      }
  }
}

extern "C" void kernel_launch(void* const* d_in, const int* in_sizes, int n_in,
                              void* d_out, int out_size, void* d_ws, size_t ws_size,
                              hipStream_t stream) {
  if (ws_size < (size_t)WS_TOTAL) return;
  char* ws = (char*)d_ws;
  int*   flag  = (int*)(ws + WS_FLAG);
  u16*   wAllT = (u16*)(ws + WS_WAT2);
  bf16*  theta = (bf16*)(ws + WS_THETA);
  bf16*  phi   = (bf16*)(ws + WS_PHI);
  bf16*  gT    = (bf16*)(ws + WS_G);
  u16*   waT   = (u16*)(ws + WS_WAT);

  detect_kernel<<<1, 256, 0, stream>>>(d_in[0], flag);

  sn_kernel<bf16><<<4, 256, 0, stream>>>(d_in[1], d_in[2], d_in[3], d_in[4],
                                         d_in[5], d_in[6], d_in[7], d_in[8],
                                         wAllT, waT, flag);
  sn_kernel<float><<<4, 256, 0, stream>>>(d_in[1], d_in[2], d_in[3], d_in[4],
                                          d_in[5], d_in[6], d_in[7], d_in[8],
                                          wAllT, waT, flag);

  conv3_mfma_kernel<bf16><<<1024, 256, 0, stream>>>(d_in[0], wAllT, theta, phi, gT, flag);
  conv3_mfma_kernel<float><<<1024, 256, 0, stream>>>(d_in[0], wAllT, theta, phi, gT, flag);

  attn_kernel<bf16><<<1024, 256, 0, stream>>>(theta, phi, gT, d_out, flag);
  attn_kernel<float><<<1024, 256, 0, stream>>>(theta, phi, gT, d_out, flag);

  proj_kernel<bf16><<<1024, 256, 0, stream>>>(waT, d_in[0], d_in[9], d_out, flag);
  proj_kernel<float><<<1024, 256, 0, stream>>>(waT, d_in[0], d_in[9], d_out, flag);
}